// Round 19
// baseline (166.881 us; speedup 1.0000x reference)
//
#include <hip/hip_runtime.h>

typedef __bf16 bf16_t;
typedef __bf16 bf16x4 __attribute__((ext_vector_type(4)));
typedef __bf16 bf16x8 __attribute__((ext_vector_type(8)));
typedef short  s16x4  __attribute__((ext_vector_type(4)));
typedef float  f32x4  __attribute__((ext_vector_type(4)));

#define NUM_B 64
#define SEQ   343
#define CH    512
#define NH    16
#define HDIM  32
#define NWIN  8
#define C3    1536
#define MTOT  (NUM_B * SEQ)      // 21952
#define MPAD  22016              // 172 * 128
#define NTILES 22
#define NTP   11                 // nt pairs
#define NPAD  352
#define NN    (SEQ * SEQ)
#define MB_TILES 172
#define QSCALE 0.17677669529663687f
#define LOG2E  1.4426950408889634f

__device__ __forceinline__ f32x4 mfma16(bf16x8 a, bf16x8 b, f32x4 c) {
    return __builtin_amdgcn_mfma_f32_16x16x32_bf16(a, b, c, 0, 0, 0);
}

// 16x16x16 bf16 MFMA: A-fragment = A[m=lane&15][k=4*(lane>>4)+e] -- matches the
// C/D layout of the swapped QK^T, so P^T needs NO data movement to become the
// PV A-operand.
__device__ __forceinline__ f32x4 mfma16k16(bf16x4 a, bf16x4 b, f32x4 c) {
    return __builtin_amdgcn_mfma_f32_16x16x16bf16_1k(
        __builtin_bit_cast(s16x4, a), __builtin_bit_cast(s16x4, b), c, 0, 0, 0);
}

__device__ __forceinline__ bf16x8 bf8_zero() {
    bf16x8 v;
#pragma unroll
    for (int i = 0; i < 8; ++i) v[i] = (bf16_t)0.f;
    return v;
}

__device__ __forceinline__ bf16x8 pack8(const float4& a, const float4& b) {
    bf16x8 v;
    v[0] = (bf16_t)a.x; v[1] = (bf16_t)a.y; v[2] = (bf16_t)a.z; v[3] = (bf16_t)a.w;
    v[4] = (bf16_t)b.x; v[5] = (bf16_t)b.y; v[6] = (bf16_t)b.z; v[7] = (bf16_t)b.w;
    return v;
}

__device__ __forceinline__ float f4get(const float4& v, int i) {
    return i == 0 ? v.x : i == 1 ? v.y : i == 2 ? v.z : v.w;
}

__device__ __forceinline__ void gload16(const void* g, void* l) {
    __builtin_amdgcn_global_load_lds(
        (const __attribute__((address_space(1))) void*)g,
        (__attribute__((address_space(3))) void*)l, 16, 0, 0);
}

// ---------------- merged prep: X->bf16, W -> MFMA-fragment layout, comb table ----
// Bfrag[n16][k32][lane][8] = W[k32*32 + (lane>>4)*8 + e][n16*16 + (lane&15)].
// comb is bf16 PAIR-PACKED: comb_pk[plane][mt][ntp][lane] is a bf16x8 =
// {nt=2*ntp r0..3, nt=2*ntp+1 r0..3} -> attn loads ONE b128 per (tile, nt-pair).
// bf16 keeps each XCD's 16-plane working set ~3.96 MB ~= L2 size (fp32 thrashed: r18).
__global__ __launch_bounds__(256) void swin_prep(
        const float* __restrict__ X, const float* __restrict__ Wq,
        const float* __restrict__ Wp, const float* __restrict__ bias_table,
        const int* __restrict__ rel_index, const float* __restrict__ mask,
        bf16_t* __restrict__ Xb, bf16_t* __restrict__ Bfq, bf16_t* __restrict__ Bfp,
        bf16_t* __restrict__ comb) {
    __shared__ __align__(16) float shbuf[32 * 33];
    const int bid = blockIdx.x, t = threadIdx.x;
    if (bid < 5504) {
        size_t e = ((size_t)bid * 256 + t) * 8;
        bf16x8 v;
        if (e < (size_t)MTOT * CH) {
            const float4* p = reinterpret_cast<const float4*>(&X[e]);
            v = pack8(p[0], p[1]);
        } else v = bf8_zero();
        *reinterpret_cast<bf16x8*>(&Xb[e]) = v;
        return;
    }
    if (bid < 6528) {
        float (*tile)[33] = reinterpret_cast<float(*)[33]>(shbuf);
        const float* src; bf16_t* dst; int srcN, k0, n0;
        if (bid < 6272) {
            int b2 = bid - 5504;               // Wq: 768 blocks (16 k-tiles x 48 n-tiles)
            k0 = (b2 % 16) * 32; n0 = (b2 / 16) * 32;
            src = Wq; dst = Bfq; srcN = C3;
        } else {
            int b2 = bid - 6272;               // Wp: 256 blocks
            k0 = (b2 % 16) * 32; n0 = (b2 / 16) * 32;
            src = Wp; dst = Bfp; srcN = CH;
        }
        int r = t >> 3, c4 = (t & 7) * 4;
        const float4 u = *reinterpret_cast<const float4*>(&src[(size_t)(k0 + r) * srcN + n0 + c4]);
        tile[r][c4 + 0] = u.x; tile[r][c4 + 1] = u.y; tile[r][c4 + 2] = u.z; tile[r][c4 + 3] = u.w;
        __syncthreads();
        // write fragment layout: t -> (sub n16-half, lane, elem-half)
        const int sub = t >> 7, lane2 = (t >> 1) & 63, half = t & 1;
        const int lm = lane2 & 15, g = lane2 >> 4;
        bf16x4 o;
#pragma unroll
        for (int e = 0; e < 4; ++e)
            o[e] = (bf16_t)tile[g * 8 + half * 4 + e][sub * 16 + lm];
        const size_t off = ((size_t)(((n0 >> 4) + sub) * 16 + (k0 >> 5)) * 64 + lane2) * 8 + half * 4;
        *reinterpret_cast<bf16x4*>(&dst[off]) = o;
        return;
    }
    // ---- comb table: cid = ((w*22 + mt)*6 + ntq), wave (t>>6) handles nt = ntq*4+(t>>6)
    const int cid = bid - 6528;
    const int ntq = cid % 6, mt = (cid / 6) % NTILES, w = cid / (6 * NTILES);
    const int nt = ntq * 4 + (t >> 6);
    if (nt >= NTILES) return;
    const int lane = t & 63;
    const int lm = lane & 15, g = lane >> 4;
    const int gm = mt * 16 + lm;
    const bool gmok = gm < SEQ;

    bool ok[4]; int idx[4]; float mv[4];
#pragma unroll
    for (int r = 0; r < 4; ++r) {
        int gn = nt * 16 + 4 * g + r;
        ok[r] = gmok && (gn < SEQ);
        int a = ok[r] ? gm * SEQ + gn : 0;
        idx[r] = rel_index[a];
        mv[r] = ok[r] ? mask[(size_t)w * NN + a] : 0.f;
    }
    // pair-packed slot: elems [((mt*11+ntp)*64+lane)*8 + (nt&1)*4 ..+3] within plane
    const int ntp = nt >> 1, par = nt & 1;
    const size_t plane_stride = (size_t)NTILES * NTP * 64 * 8;   // 123904 elems
    const size_t slot = ((size_t)(mt * NTP + ntp) * 64 + lane) * 8 + par * 4;
#pragma unroll
    for (int hq = 0; hq < 4; ++hq) {
        float4 b0 = *reinterpret_cast<const float4*>(&bias_table[idx[0] * NH + hq * 4]);
        float4 b1 = *reinterpret_cast<const float4*>(&bias_table[idx[1] * NH + hq * 4]);
        float4 b2 = *reinterpret_cast<const float4*>(&bias_table[idx[2] * NH + hq * 4]);
        float4 b3 = *reinterpret_cast<const float4*>(&bias_table[idx[3] * NH + hq * 4]);
#pragma unroll
        for (int hh = 0; hh < 4; ++hh) {
            int h = hq * 4 + hh;
            bf16x4 o;
            o[0] = ok[0] ? (bf16_t)((f4get(b0, hh) + mv[0]) * LOG2E) : (bf16_t)(-1e30f);
            o[1] = ok[1] ? (bf16_t)((f4get(b1, hh) + mv[1]) * LOG2E) : (bf16_t)(-1e30f);
            o[2] = ok[2] ? (bf16_t)((f4get(b2, hh) + mv[2]) * LOG2E) : (bf16_t)(-1e30f);
            o[3] = ok[3] ? (bf16_t)((f4get(b3, hh) + mv[3]) * LOG2E) : (bf16_t)(-1e30f);
            *reinterpret_cast<bf16x4*>(&comb[(size_t)(h * 8 + w) * plane_stride + slot]) = o;
        }
    }
}

// ---------------- pipelined bf16 GEMM: C = A[M][512] * W, B from L2 ----------------
// A: BK=32, 3-buffer LDS ring (24 KB), counted vmcnt, STAGE after barrier (race-free).
// B: MFMA-fragment loads straight from Bfrag (L2-resident), DEPTH-1 pipelined
// (bc <- bn). Depth-2 regressed (r17): +12 VGPR crossed an allocation step and cost
// a block/CU. 80 VGPR / 3 blocks/CU verified at 49.6 us.
template <int NB, bool QKV>
__global__ __launch_bounds__(256) void swin_gemm(
        const bf16_t* __restrict__ A, const bf16_t* __restrict__ Bf,
        const float* __restrict__ bias, void* __restrict__ outv) {
    __shared__ __align__(16) bf16_t shraw[17408];         // 34816 B: ring 24576 | epilogue
    const int nwg8 = MB_TILES * NB / 8;
    int bid = blockIdx.x;
    bid = (bid & 7) * nwg8 + (bid >> 3);                  // XCD-chunked swizzle
    const int nb = bid % NB, mb = bid / NB;
    const int m0 = mb * 128, n0 = nb * 128;
    const int t = threadIdx.x, wid = t >> 6, lane = t & 63;
    const int wr = wid >> 1, wc = wid & 1;
    const int lm = lane & 15, g = lane >> 4;
    const int swr = ((lane >> 2) ^ (lane >> 4)) & 3;
    const bf16_t* gA = &A[(size_t)(m0 + wid * 32 + (lane >> 2)) * CH + (((lane & 3) ^ swr) << 3)];
    const int soff = ((g ^ ((lm ^ (lm >> 2)) & 3)) << 3);
    // B fragment base: n16 tiles (n0>>4)+wc*4+j, k32 tile = kt; 8192 elems per n16
    const bf16_t* gBf = &Bf[((size_t)((n0 >> 4) + wc * 4) * 16) * 512 + lane * 8];

    f32x4 acc[4][4];
#pragma unroll
    for (int i = 0; i < 4; ++i)
#pragma unroll
        for (int j = 0; j < 4; ++j) {
            acc[i][j][0] = 0.f; acc[i][j][1] = 0.f; acc[i][j][2] = 0.f; acc[i][j][3] = 0.f;
        }

#define STAGE(tile, buf)                                                          \
    do {                                                                          \
        const int _k0 = (tile) * 32;                                              \
        gload16(gA + _k0,           &shraw[(buf) * 4096 + (wid * 32 + 0) * 32]);  \
        gload16(gA + _k0 + 16 * CH, &shraw[(buf) * 4096 + (wid * 32 + 16) * 32]); \
    } while (0)

    STAGE(0, 0);
    STAGE(1, 1);
    bf16x8 bc[4], bn[4];
#pragma unroll
    for (int j = 0; j < 4; ++j)
        bc[j] = *reinterpret_cast<const bf16x8*>(gBf + (size_t)j * 8192);

#pragma unroll
    for (int kt = 0; kt < 16; ++kt) {
        // outstanding at most: A-stage(kt+1) [2] + b(kt) [4] -> stage(kt) is older, done
        if (kt <= 14) asm volatile("s_waitcnt vmcnt(6)" ::: "memory");
        else          asm volatile("s_waitcnt vmcnt(4)" ::: "memory");
        __builtin_amdgcn_s_barrier();
        __builtin_amdgcn_sched_barrier(0);
        if (kt <= 13) STAGE(kt + 2, (kt + 2) % 3);        // after barrier: 3-ring safe
        if (kt <= 14) {
#pragma unroll
            for (int j = 0; j < 4; ++j)
                bn[j] = *reinterpret_cast<const bf16x8*>(gBf + (size_t)j * 8192 + (kt + 1) * 512);
        }
        const int buf = kt % 3;
        bf16x8 a[4];
#pragma unroll
        for (int i = 0; i < 4; ++i)
            a[i] = *reinterpret_cast<const bf16x8*>(&shraw[buf * 4096 + (wr * 64 + i * 16 + lm) * 32 + soff]);
        __builtin_amdgcn_s_setprio(1);
#pragma unroll
        for (int i = 0; i < 4; ++i)
#pragma unroll
            for (int j = 0; j < 4; ++j)
                acc[i][j] = mfma16(a[i], bc[j], acc[i][j]);
        __builtin_amdgcn_s_setprio(0);
        if (kt <= 14) {
#pragma unroll
            for (int j = 0; j < 4; ++j) bc[j] = bn[j];
        }
    }
#undef STAGE
    __syncthreads();   // full drain once before LDS reuse in epilogue

    // epilogue: LDS transpose -> coalesced stores
    const int rb = (lane >> 4) << 2;
    if (QKV) {
        bf16_t* Cs = &shraw[0];                           // [128][136] bf16 = 34816 B
#pragma unroll
        for (int j = 0; j < 4; ++j) {
            int col = wc * 64 + j * 16 + lm;
            float bv = bias[n0 + col];
            float sc = (n0 + col < CH) ? (QSCALE * LOG2E) : 1.0f;   // Q pre-scale incl. log2e
#pragma unroll
            for (int i = 0; i < 4; ++i)
#pragma unroll
                for (int r = 0; r < 4; ++r)
                    Cs[(wr * 64 + i * 16 + rb + r) * 136 + col] = (bf16_t)((acc[i][j][r] + bv) * sc);
        }
        __syncthreads();
        bf16_t* outp = (bf16_t*)outv;
#pragma unroll
        for (int it = 0; it < 8; ++it) {
            int row = (t >> 4) + it * 16;
            int c8 = (t & 15) * 8;
            bf16x8 v = *reinterpret_cast<const bf16x8*>(&Cs[row * 136 + c8]);
            int grow = m0 + row;
            if (grow < MTOT)
                *reinterpret_cast<bf16x8*>(&outp[(size_t)grow * (NB * 128) + n0 + c8]) = v;
        }
    } else {
        // fp32 transpose in two 64-row halves (32 KB each, fits 34816 B)
        float* fCs = reinterpret_cast<float*>(&shraw[0]);     // [64][128] fp32
        float* outp = (float*)outv;
#pragma unroll
        for (int half = 0; half < 2; ++half) {
            __syncthreads();
            if (wr == half) {
#pragma unroll
                for (int j = 0; j < 4; ++j) {
                    int col = wc * 64 + j * 16 + lm;
                    float bv = bias[n0 + col];
#pragma unroll
                    for (int i = 0; i < 4; ++i)
#pragma unroll
                        for (int r = 0; r < 4; ++r)
                            fCs[(i * 16 + rb + r) * 128 + col] = acc[i][j][r] + bv;
                }
            }
            __syncthreads();
#pragma unroll
            for (int it = 0; it < 8; ++it) {
                int row = (t >> 5) + it * 8;              // 0..63
                int c4 = (t & 31) * 4;
                float4 v = *reinterpret_cast<const float4*>(&fCs[row * 128 + c4]);
                int grow = m0 + half * 64 + row;
                if (grow < MTOT)
                    *reinterpret_cast<float4*>(&outp[(size_t)grow * (NB * 128) + n0 + c4]) = v;
            }
        }
    }
}

// ---------------- attention: one block (8 waves) per (b,h); single-pass streaming.
// Swapped QK^T (bf16 comb rides as MFMA C-init) -> raw exp2 -> PV via 16x16x16 MFMAs
// (A-fragment == QK^T C/D layout). Denominator via ones-MFMA. PAIRED m-tiles
// (mt=w, w+8) share kf/v0/v1 LDS reads; comb is pair-packed (one b128 covers the
// nt-pair). Tail tile (mt=w+16, w<6). All accumulators distinct named vars (rule #20).
__global__ __launch_bounds__(512, 6) void swin_attn(
        const bf16_t* __restrict__ qkv, const bf16_t* __restrict__ comb,
        bf16_t* __restrict__ attout) {
    __shared__ __align__(16) bf16_t Ksh[NPAD * 32];       // [n][d], swz ((n>>1)&3)<<3
    __shared__ __align__(16) bf16_t Vsh[32 * NPAD];       // [d][n], swz ((d>>1)&3)<<3
    const int t = threadIdx.x;
    const int bid = blockIdx.x;
    const int h = (bid & 127) >> 3;
    const int w = bid & 7;
    const int b = w + ((bid >> 7) << 3);                  // b = w + 8*j
    const int plane = h * 8 + w;
    const int wid = t >> 6, lane = t & 63;
    const int lm = lane & 15, g = lane >> 4;
    const int lkb = g << 3;
    const size_t rowbase = (size_t)b * SEQ;

    // stage K rows + V^T
    for (int base = 0; base < SEQ; base += 128) {
        int n = base + (t >> 2);
        int db = (t & 3) << 3;
        if (n < SEQ) {
            bf16x8 kv = *reinterpret_cast<const bf16x8*>(&qkv[(rowbase + n) * C3 + CH + h * HDIM + db]);
            *reinterpret_cast<bf16x8*>(&Ksh[(n * 32 + db) ^ (((n >> 1) & 3) << 3)]) = kv;
            bf16x8 vv = *reinterpret_cast<const bf16x8*>(&qkv[(rowbase + n) * C3 + 2 * CH + h * HDIM + db]);
#pragma unroll
            for (int e = 0; e < 8; ++e) {
                int d = db + e;
                Vsh[(d * NPAD + n) ^ (((d >> 1) & 3) << 3)] = vv[e];
            }
        }
    }
    if (t < 36) {
        int n = SEQ + (t >> 2), db = (t & 3) << 3;
        *reinterpret_cast<bf16x8*>(&Ksh[(n * 32 + db) ^ (((n >> 1) & 3) << 3)]) = bf8_zero();
    }
    for (int i = t; i < 32 * 9; i += 512) {
        int d = i / 9, n = SEQ + (i % 9);
        Vsh[(d * NPAD + n) ^ (((d >> 1) & 3) << 3)] = (bf16_t)0.f;
    }
    __syncthreads();

    const int kswz = ((lm >> 1) & 3) << 3;
    const int kbase = (lm * 32 + lkb) ^ kswz;       // K reads: base + nt*512 (imm offsets)
    const int vb0e = (lm * NPAD + 4 * g) ^ kswz;
    const int vb0o = (lm * NPAD + 4 * g + 16) ^ kswz;
    const int vb1e = ((16 + lm) * NPAD + 4 * g) ^ kswz;
    const int vb1o = ((16 + lm) * NPAD + 4 * g + 16) ^ kswz;
    const size_t plane_stride = (size_t)NTILES * NTP * 64;   // in bf16x8 units

    bf16x4 ones;
    ones[0] = (bf16_t)1.f; ones[1] = (bf16_t)1.f; ones[2] = (bf16_t)1.f; ones[3] = (bf16_t)1.f;

    // ---- paired tiles: mt_a = wid, mt_b = wid + 8 (both always < 22)
    {
        const int m0a = wid * 16, m0b = (wid + 8) * 16;
        bf16x8 qfa = *reinterpret_cast<const bf16x8*>(&qkv[(rowbase + m0a + lm) * C3 + h * HDIM + lkb]);
        bf16x8 qfb = *reinterpret_cast<const bf16x8*>(&qkv[(rowbase + m0b + lm) * C3 + h * HDIM + lkb]);

        f32x4 o0a = {0.f, 0.f, 0.f, 0.f}, o1a = {0.f, 0.f, 0.f, 0.f}, osa = {0.f, 0.f, 0.f, 0.f};
        f32x4 o0b = {0.f, 0.f, 0.f, 0.f}, o1b = {0.f, 0.f, 0.f, 0.f}, osb = {0.f, 0.f, 0.f, 0.f};
        const bf16x8* cpa = reinterpret_cast<const bf16x8*>(comb) + plane * plane_stride + (size_t)wid * NTP * 64;
        const bf16x8* cpb = cpa + (size_t)8 * NTP * 64;
#pragma unroll 2
        for (int ntp = 0; ntp < NTP; ++ntp) {
            bf16x8 ca = cpa[ntp * 64 + lane];     // {nt even r0..3, nt odd r0..3}
            bf16x8 cb = cpb[ntp * 64 + lane];
            const int off = ntp * 32;
            // ---- nt even
            {
                bf16x8 kf = *reinterpret_cast<const bf16x8*>(&Ksh[kbase + (2 * ntp) * 512]);
                f32x4 za, zb;
                za[0] = (float)ca[0]; za[1] = (float)ca[1]; za[2] = (float)ca[2]; za[3] = (float)ca[3];
                zb[0] = (float)cb[0]; zb[1] = (float)cb[1]; zb[2] = (float)cb[2]; zb[3] = (float)cb[3];
                f32x4 sa = mfma16(kf, qfa, za);
                f32x4 sb = mfma16(kf, qfb, zb);
                bf16x4 paa, pab;
#pragma unroll
                for (int r = 0; r < 4; ++r) {
                    paa[r] = (bf16_t)__builtin_amdgcn_exp2f(sa[r]);
                    pab[r] = (bf16_t)__builtin_amdgcn_exp2f(sb[r]);
                }
                bf16x4 v0 = *reinterpret_cast<const bf16x4*>(&Vsh[vb0e + off]);
                bf16x4 v1 = *reinterpret_cast<const bf16x4*>(&Vsh[vb1e + off]);
                o0a = mfma16k16(paa, v0, o0a);
                o0b = mfma16k16(pab, v0, o0b);
                o1a = mfma16k16(paa, v1, o1a);
                o1b = mfma16k16(pab, v1, o1b);
                osa = mfma16k16(paa, ones, osa);
                osb = mfma16k16(pab, ones, osb);
            }
            // ---- nt odd
            {
                bf16x8 kf = *reinterpret_cast<const bf16x8*>(&Ksh[kbase + (2 * ntp + 1) * 512]);
                f32x4 za, zb;
                za[0] = (float)ca[4]; za[1] = (float)ca[5]; za[2] = (float)ca[6]; za[3] = (float)ca[7];
                zb[0] = (float)cb[4]; zb[1] = (float)cb[5]; zb[2] = (float)cb[6]; zb[3] = (float)cb[7];
                f32x4 sa = mfma16(kf, qfa, za);
                f32x4 sb = mfma16(kf, qfb, zb);
                bf16x4 paa, pab;
#pragma unroll
                for (int r = 0; r < 4; ++r) {
                    paa[r] = (bf16_t)__builtin_amdgcn_exp2f(sa[r]);
                    pab[r] = (bf16_t)__builtin_amdgcn_exp2f(sb[r]);
                }
                bf16x4 v0 = *reinterpret_cast<const bf16x4*>(&Vsh[vb0o + off]);
                bf16x4 v1 = *reinterpret_cast<const bf16x4*>(&Vsh[vb1o + off]);
                o0a = mfma16k16(paa, v0, o0a);
                o0b = mfma16k16(pab, v0, o0b);
                o1a = mfma16k16(paa, v1, o1a);
                o1b = mfma16k16(pab, v1, o1b);
                osa = mfma16k16(paa, ones, osa);
                osb = mfma16k16(pab, ones, osb);
            }
        }
#pragma unroll
        for (int r = 0; r < 4; ++r) {
            int gma = m0a + 4 * g + r;
            float iva = 1.f / osa[r];
            attout[(rowbase + gma) * CH + h * HDIM + lm]      = (bf16_t)(o0a[r] * iva);
            attout[(rowbase + gma) * CH + h * HDIM + 16 + lm] = (bf16_t)(o1a[r] * iva);
            int gmb = m0b + 4 * g + r;
            float ivb = 1.f / osb[r];
            attout[(rowbase + gmb) * CH + h * HDIM + lm]      = (bf16_t)(o0b[r] * ivb);
            attout[(rowbase + gmb) * CH + h * HDIM + 16 + lm] = (bf16_t)(o1b[r] * ivb);
        }
    }

    // ---- tail tile: mt = wid + 16 (only waves 0..5)
    if (wid < 6) {
        const int mt = wid + 16;
        const int m0 = mt * 16;
        // out-of-range q-rows read allocated pad rows; comb pad (-1e30) zeroes them
        bf16x8 qf = *reinterpret_cast<const bf16x8*>(&qkv[(rowbase + m0 + lm) * C3 + h * HDIM + lkb]);

        f32x4 o0 = {0.f, 0.f, 0.f, 0.f}, o1 = {0.f, 0.f, 0.f, 0.f};
        f32x4 osum = {0.f, 0.f, 0.f, 0.f};
        const bf16x8* cp = reinterpret_cast<const bf16x8*>(comb) + plane * plane_stride + (size_t)mt * NTP * 64;
#pragma unroll 2
        for (int ntp = 0; ntp < NTP; ++ntp) {
            bf16x8 cc = cp[ntp * 64 + lane];
            const int off = ntp * 32;
            {
                bf16x8 kf = *reinterpret_cast<const bf16x8*>(&Ksh[kbase + (2 * ntp) * 512]);
                f32x4 z;
                z[0] = (float)cc[0]; z[1] = (float)cc[1]; z[2] = (float)cc[2]; z[3] = (float)cc[3];
                f32x4 s = mfma16(kf, qf, z);
                bf16x4 pa;
#pragma unroll
                for (int r = 0; r < 4; ++r)
                    pa[r] = (bf16_t)__builtin_amdgcn_exp2f(s[r]);
                bf16x4 v0 = *reinterpret_cast<const bf16x4*>(&Vsh[vb0e + off]);
                bf16x4 v1 = *reinterpret_cast<const bf16x4*>(&Vsh[vb1e + off]);
                o0 = mfma16k16(pa, v0, o0);
                o1 = mfma16k16(pa, v1, o1);
                osum = mfma16k16(pa, ones, osum);
            }
            {
                bf16x8 kf = *reinterpret_cast<const bf16x8*>(&Ksh[kbase + (2 * ntp + 1) * 512]);
                f32x4 z;
                z[0] = (float)cc[4]; z[1] = (float)cc[5]; z[2] = (float)cc[6]; z[3] = (float)cc[7];
                f32x4 s = mfma16(kf, qf, z);
                bf16x4 pa;
#pragma unroll
                for (int r = 0; r < 4; ++r)
                    pa[r] = (bf16_t)__builtin_amdgcn_exp2f(s[r]);
                bf16x4 v0 = *reinterpret_cast<const bf16x4*>(&Vsh[vb0o + off]);
                bf16x4 v1 = *reinterpret_cast<const bf16x4*>(&Vsh[vb1o + off]);
                o0 = mfma16k16(pa, v0, o0);
                o1 = mfma16k16(pa, v1, o1);
                osum = mfma16k16(pa, ones, osum);
            }
        }
#pragma unroll
        for (int r = 0; r < 4; ++r) {
            int gm = m0 + 4 * g + r;
            if (gm < SEQ) {
                float iv = 1.f / osum[r];
                attout[(rowbase + gm) * CH + h * HDIM + lm]      = (bf16_t)(o0[r] * iv);
                attout[(rowbase + gm) * CH + h * HDIM + 16 + lm] = (bf16_t)(o1[r] * iv);
            }
        }
    }
}

extern "C" void kernel_launch(void* const* d_in, const int* in_sizes, int n_in,
                              void* d_out, int out_size, void* d_ws, size_t ws_size,
                              hipStream_t stream) {
    const float* x          = (const float*)d_in[0];
    const float* mask       = (const float*)d_in[1];
    const float* w_qkv      = (const float*)d_in[2];
    const float* b_qkv      = (const float*)d_in[3];
    const float* w_proj     = (const float*)d_in[4];
    const float* b_proj     = (const float*)d_in[5];
    const float* bias_table = (const float*)d_in[6];
    const int*   rel_index  = (const int*)d_in[7];
    float* out = (float*)d_out;

    char* ws = (char*)d_ws;
    const size_t qkv_bytes = (size_t)MPAD * C3 * sizeof(bf16_t);   // 67,633,152
    const size_t xb_bytes  = (size_t)MPAD * CH * sizeof(bf16_t);   // 22,544,384
    const size_t bfq_bytes = (size_t)C3 * CH * sizeof(bf16_t);     //  1,572,864
    const size_t bfp_bytes = (size_t)CH * CH * sizeof(bf16_t);     //    524,288
    bf16_t* qkv    = (bf16_t*)ws;
    bf16_t* Xb     = (bf16_t*)(ws + qkv_bytes);           // reused as attout
    bf16_t* attout = Xb;
    bf16_t* Bfq    = (bf16_t*)(ws + qkv_bytes + xb_bytes);
    bf16_t* Bfp    = (bf16_t*)(ws + qkv_bytes + xb_bytes + bfq_bytes);
    bf16_t* comb   = (bf16_t*)(ws + qkv_bytes + xb_bytes + bfq_bytes + bfp_bytes);
    // comb bf16 pair-packed: 128 planes x 123904 elems x 2 B = 31.7 MB

    const int prep_grid = 5504 + 768 + 256 + NWIN * NTILES * 6;   // 6528 + 1056 = 7584
    hipLaunchKernelGGL(swin_prep, dim3(prep_grid), dim3(256), 0, stream,
                       x, w_qkv, w_proj, bias_table, rel_index, mask, Xb, Bfq, Bfp, comb);
    hipLaunchKernelGGL((swin_gemm<12, true>), dim3(MB_TILES * 12), dim3(256), 0, stream,
                       Xb, Bfq, b_qkv, (void*)qkv);
    hipLaunchKernelGGL(swin_attn, dim3(NUM_B * NH), dim3(512), 0, stream,
                       qkv, comb, attout);
    hipLaunchKernelGGL((swin_gemm<4, false>), dim3(MB_TILES * 4), dim3(256), 0, stream,
                       attout, Bfp, b_proj, (void*)out);
}

// Round 20
// 146.173 us; speedup vs baseline: 1.1417x; 1.1417x over previous
//
#include <hip/hip_runtime.h>

typedef __bf16 bf16_t;
typedef __bf16 bf16x4 __attribute__((ext_vector_type(4)));
typedef __bf16 bf16x8 __attribute__((ext_vector_type(8)));
typedef short  s16x4  __attribute__((ext_vector_type(4)));
typedef float  f32x4  __attribute__((ext_vector_type(4)));

#define NUM_B 64
#define SEQ   343
#define CH    512
#define NH    16
#define HDIM  32
#define NWIN  8
#define C3    1536
#define MTOT  (NUM_B * SEQ)      // 21952
#define MPAD  22016              // 172 * 128
#define NTILES 22
#define NPAD  352
#define NN    (SEQ * SEQ)
#define MB_TILES 172
#define QSCALE 0.17677669529663687f
#define LOG2E  1.4426950408889634f

__device__ __forceinline__ f32x4 mfma16(bf16x8 a, bf16x8 b, f32x4 c) {
    return __builtin_amdgcn_mfma_f32_16x16x32_bf16(a, b, c, 0, 0, 0);
}

// 16x16x16 bf16 MFMA: A-fragment = A[m=lane&15][k=4*(lane>>4)+e] -- matches the
// C/D layout of the swapped QK^T, so P^T needs NO data movement to become the
// PV A-operand.
__device__ __forceinline__ f32x4 mfma16k16(bf16x4 a, bf16x4 b, f32x4 c) {
    return __builtin_amdgcn_mfma_f32_16x16x16bf16_1k(
        __builtin_bit_cast(s16x4, a), __builtin_bit_cast(s16x4, b), c, 0, 0, 0);
}

__device__ __forceinline__ bf16x8 bf8_zero() {
    bf16x8 v;
#pragma unroll
    for (int i = 0; i < 8; ++i) v[i] = (bf16_t)0.f;
    return v;
}

__device__ __forceinline__ bf16x8 pack8(const float4& a, const float4& b) {
    bf16x8 v;
    v[0] = (bf16_t)a.x; v[1] = (bf16_t)a.y; v[2] = (bf16_t)a.z; v[3] = (bf16_t)a.w;
    v[4] = (bf16_t)b.x; v[5] = (bf16_t)b.y; v[6] = (bf16_t)b.z; v[7] = (bf16_t)b.w;
    return v;
}

__device__ __forceinline__ float f4get(const float4& v, int i) {
    return i == 0 ? v.x : i == 1 ? v.y : i == 2 ? v.z : v.w;
}

__device__ __forceinline__ void gload16(const void* g, void* l) {
    __builtin_amdgcn_global_load_lds(
        (const __attribute__((address_space(1))) void*)g,
        (__attribute__((address_space(3))) void*)l, 16, 0, 0);
}

// ---------------- merged prep: X->bf16, W -> MFMA-fragment layout, comb table ----
// Bfrag[n16][k32][lane][8] = W[k32*32 + (lane>>4)*8 + e][n16*16 + (lane&15)]:
// a wave's B-operand (16 cols x K=32) is ONE contiguous 1KB chunk -> B never
// touches LDS in the GEMM (L2-resident weights), halving GEMM LDS traffic.
// comb bf16 (16 planes/XCD ~= 3.96 MB ~= L2; fp32 thrashed L2, r18).
__global__ __launch_bounds__(256) void swin_prep(
        const float* __restrict__ X, const float* __restrict__ Wq,
        const float* __restrict__ Wp, const float* __restrict__ bias_table,
        const int* __restrict__ rel_index, const float* __restrict__ mask,
        bf16_t* __restrict__ Xb, bf16_t* __restrict__ Bfq, bf16_t* __restrict__ Bfp,
        bf16_t* __restrict__ comb) {
    __shared__ __align__(16) float shbuf[32 * 33];
    const int bid = blockIdx.x, t = threadIdx.x;
    if (bid < 5504) {
        size_t e = ((size_t)bid * 256 + t) * 8;
        bf16x8 v;
        if (e < (size_t)MTOT * CH) {
            const float4* p = reinterpret_cast<const float4*>(&X[e]);
            v = pack8(p[0], p[1]);
        } else v = bf8_zero();
        *reinterpret_cast<bf16x8*>(&Xb[e]) = v;
        return;
    }
    if (bid < 6528) {
        float (*tile)[33] = reinterpret_cast<float(*)[33]>(shbuf);
        const float* src; bf16_t* dst; int srcN, k0, n0;
        if (bid < 6272) {
            int b2 = bid - 5504;               // Wq: 768 blocks (16 k-tiles x 48 n-tiles)
            k0 = (b2 % 16) * 32; n0 = (b2 / 16) * 32;
            src = Wq; dst = Bfq; srcN = C3;
        } else {
            int b2 = bid - 6272;               // Wp: 256 blocks
            k0 = (b2 % 16) * 32; n0 = (b2 / 16) * 32;
            src = Wp; dst = Bfp; srcN = CH;
        }
        int r = t >> 3, c4 = (t & 7) * 4;
        const float4 u = *reinterpret_cast<const float4*>(&src[(size_t)(k0 + r) * srcN + n0 + c4]);
        tile[r][c4 + 0] = u.x; tile[r][c4 + 1] = u.y; tile[r][c4 + 2] = u.z; tile[r][c4 + 3] = u.w;
        __syncthreads();
        // write fragment layout: t -> (sub n16-half, lane, elem-half)
        const int sub = t >> 7, lane2 = (t >> 1) & 63, half = t & 1;
        const int lm = lane2 & 15, g = lane2 >> 4;
        bf16x4 o;
#pragma unroll
        for (int e = 0; e < 4; ++e)
            o[e] = (bf16_t)tile[g * 8 + half * 4 + e][sub * 16 + lm];
        const size_t off = ((size_t)(((n0 >> 4) + sub) * 16 + (k0 >> 5)) * 64 + lane2) * 8 + half * 4;
        *reinterpret_cast<bf16x4*>(&dst[off]) = o;
        return;
    }
    // ---- comb table: cid = ((w*22 + mt)*6 + ntq), wave (t>>6) handles nt = ntq*4+(t>>6)
    const int cid = bid - 6528;
    const int ntq = cid % 6, mt = (cid / 6) % NTILES, w = cid / (6 * NTILES);
    const int nt = ntq * 4 + (t >> 6);
    if (nt >= NTILES) return;
    const int lane = t & 63;
    const int lm = lane & 15, g = lane >> 4;
    const int gm = mt * 16 + lm;
    const bool gmok = gm < SEQ;

    bool ok[4]; int idx[4]; float mv[4];
#pragma unroll
    for (int r = 0; r < 4; ++r) {
        int gn = nt * 16 + 4 * g + r;
        ok[r] = gmok && (gn < SEQ);
        int a = ok[r] ? gm * SEQ + gn : 0;
        idx[r] = rel_index[a];
        mv[r] = ok[r] ? mask[(size_t)w * NN + a] : 0.f;
    }
    const size_t outb = ((size_t)mt * NTILES + nt) * 64 + lane;   // bf16x4 units, within plane
    bf16x4* combv = reinterpret_cast<bf16x4*>(comb);
#pragma unroll
    for (int hq = 0; hq < 4; ++hq) {
        float4 b0 = *reinterpret_cast<const float4*>(&bias_table[idx[0] * NH + hq * 4]);
        float4 b1 = *reinterpret_cast<const float4*>(&bias_table[idx[1] * NH + hq * 4]);
        float4 b2 = *reinterpret_cast<const float4*>(&bias_table[idx[2] * NH + hq * 4]);
        float4 b3 = *reinterpret_cast<const float4*>(&bias_table[idx[3] * NH + hq * 4]);
#pragma unroll
        for (int hh = 0; hh < 4; ++hh) {
            int h = hq * 4 + hh;
            bf16x4 o;
            o[0] = ok[0] ? (bf16_t)((f4get(b0, hh) + mv[0]) * LOG2E) : (bf16_t)(-1e30f);
            o[1] = ok[1] ? (bf16_t)((f4get(b1, hh) + mv[1]) * LOG2E) : (bf16_t)(-1e30f);
            o[2] = ok[2] ? (bf16_t)((f4get(b2, hh) + mv[2]) * LOG2E) : (bf16_t)(-1e30f);
            o[3] = ok[3] ? (bf16_t)((f4get(b3, hh) + mv[3]) * LOG2E) : (bf16_t)(-1e30f);
            combv[(size_t)(h * 8 + w) * (NTILES * NTILES * 64) + outb] = o;
        }
    }
}

// ---------------- pipelined bf16 GEMM: C = A[M][512] * W, B from L2 ----------------
// A: BK=32, 3-buffer LDS ring (24 KB), counted vmcnt, STAGE after barrier (race-free).
// B: MFMA-fragment loads straight from Bfrag (L2-resident), DEPTH-1 pipelined
// (bc <- bn). Depth-2 regressed (r17): +12 VGPR crossed an allocation step and cost
// a block/CU (Occ 24.8->17.1). 80 VGPR / 3 blocks/CU verified at 49.6 us.
template <int NB, bool QKV>
__global__ __launch_bounds__(256) void swin_gemm(
        const bf16_t* __restrict__ A, const bf16_t* __restrict__ Bf,
        const float* __restrict__ bias, void* __restrict__ outv) {
    __shared__ __align__(16) bf16_t shraw[17408];         // 34816 B: ring 24576 | epilogue
    const int nwg8 = MB_TILES * NB / 8;
    int bid = blockIdx.x;
    bid = (bid & 7) * nwg8 + (bid >> 3);                  // XCD-chunked swizzle
    const int nb = bid % NB, mb = bid / NB;
    const int m0 = mb * 128, n0 = nb * 128;
    const int t = threadIdx.x, wid = t >> 6, lane = t & 63;
    const int wr = wid >> 1, wc = wid & 1;
    const int lm = lane & 15, g = lane >> 4;
    const int swr = ((lane >> 2) ^ (lane >> 4)) & 3;
    const bf16_t* gA = &A[(size_t)(m0 + wid * 32 + (lane >> 2)) * CH + (((lane & 3) ^ swr) << 3)];
    const int soff = ((g ^ ((lm ^ (lm >> 2)) & 3)) << 3);
    // B fragment base: n16 tiles (n0>>4)+wc*4+j, k32 tile = kt; 8192 elems per n16
    const bf16_t* gBf = &Bf[((size_t)((n0 >> 4) + wc * 4) * 16) * 512 + lane * 8];

    f32x4 acc[4][4];
#pragma unroll
    for (int i = 0; i < 4; ++i)
#pragma unroll
        for (int j = 0; j < 4; ++j) {
            acc[i][j][0] = 0.f; acc[i][j][1] = 0.f; acc[i][j][2] = 0.f; acc[i][j][3] = 0.f;
        }

#define STAGE(tile, buf)                                                          \
    do {                                                                          \
        const int _k0 = (tile) * 32;                                              \
        gload16(gA + _k0,           &shraw[(buf) * 4096 + (wid * 32 + 0) * 32]);  \
        gload16(gA + _k0 + 16 * CH, &shraw[(buf) * 4096 + (wid * 32 + 16) * 32]); \
    } while (0)

    STAGE(0, 0);
    STAGE(1, 1);
    bf16x8 bc[4], bn[4];
#pragma unroll
    for (int j = 0; j < 4; ++j)
        bc[j] = *reinterpret_cast<const bf16x8*>(gBf + (size_t)j * 8192);

#pragma unroll
    for (int kt = 0; kt < 16; ++kt) {
        // outstanding at most: A-stage(kt+1) [2] + b(kt) [4] -> stage(kt) is older, done
        if (kt <= 14) asm volatile("s_waitcnt vmcnt(6)" ::: "memory");
        else          asm volatile("s_waitcnt vmcnt(4)" ::: "memory");
        __builtin_amdgcn_s_barrier();
        __builtin_amdgcn_sched_barrier(0);
        if (kt <= 13) STAGE(kt + 2, (kt + 2) % 3);        // after barrier: 3-ring safe
        if (kt <= 14) {
#pragma unroll
            for (int j = 0; j < 4; ++j)
                bn[j] = *reinterpret_cast<const bf16x8*>(gBf + (size_t)j * 8192 + (kt + 1) * 512);
        }
        const int buf = kt % 3;
        bf16x8 a[4];
#pragma unroll
        for (int i = 0; i < 4; ++i)
            a[i] = *reinterpret_cast<const bf16x8*>(&shraw[buf * 4096 + (wr * 64 + i * 16 + lm) * 32 + soff]);
        __builtin_amdgcn_s_setprio(1);
#pragma unroll
        for (int i = 0; i < 4; ++i)
#pragma unroll
            for (int j = 0; j < 4; ++j)
                acc[i][j] = mfma16(a[i], bc[j], acc[i][j]);
        __builtin_amdgcn_s_setprio(0);
        if (kt <= 14) {
#pragma unroll
            for (int j = 0; j < 4; ++j) bc[j] = bn[j];
        }
    }
#undef STAGE
    __syncthreads();   // full drain once before LDS reuse in epilogue

    // epilogue: LDS transpose -> coalesced stores
    const int rb = (lane >> 4) << 2;
    if (QKV) {
        bf16_t* Cs = &shraw[0];                           // [128][136] bf16 = 34816 B
#pragma unroll
        for (int j = 0; j < 4; ++j) {
            int col = wc * 64 + j * 16 + lm;
            float bv = bias[n0 + col];
            float sc = (n0 + col < CH) ? (QSCALE * LOG2E) : 1.0f;   // Q pre-scale incl. log2e
#pragma unroll
            for (int i = 0; i < 4; ++i)
#pragma unroll
                for (int r = 0; r < 4; ++r)
                    Cs[(wr * 64 + i * 16 + rb + r) * 136 + col] = (bf16_t)((acc[i][j][r] + bv) * sc);
        }
        __syncthreads();
        bf16_t* outp = (bf16_t*)outv;
#pragma unroll
        for (int it = 0; it < 8; ++it) {
            int row = (t >> 4) + it * 16;
            int c8 = (t & 15) * 8;
            bf16x8 v = *reinterpret_cast<const bf16x8*>(&Cs[row * 136 + c8]);
            int grow = m0 + row;
            if (grow < MTOT)
                *reinterpret_cast<bf16x8*>(&outp[(size_t)grow * (NB * 128) + n0 + c8]) = v;
        }
    } else {
        // fp32 transpose in two 64-row halves (32 KB each, fits 34816 B)
        float* fCs = reinterpret_cast<float*>(&shraw[0]);     // [64][128] fp32
        float* outp = (float*)outv;
#pragma unroll
        for (int half = 0; half < 2; ++half) {
            __syncthreads();
            if (wr == half) {
#pragma unroll
                for (int j = 0; j < 4; ++j) {
                    int col = wc * 64 + j * 16 + lm;
                    float bv = bias[n0 + col];
#pragma unroll
                    for (int i = 0; i < 4; ++i)
#pragma unroll
                        for (int r = 0; r < 4; ++r)
                            fCs[(i * 16 + rb + r) * 128 + col] = acc[i][j][r] + bv;
                }
            }
            __syncthreads();
#pragma unroll
            for (int it = 0; it < 8; ++it) {
                int row = (t >> 5) + it * 8;              // 0..63
                int c4 = (t & 31) * 4;
                float4 v = *reinterpret_cast<const float4*>(&fCs[row * 128 + c4]);
                int grow = m0 + half * 64 + row;
                if (grow < MTOT)
                    *reinterpret_cast<float4*>(&outp[(size_t)grow * (NB * 128) + n0 + c4]) = v;
            }
        }
    }
}

// ---------------- attention: one block (8 waves) per (b,h); single-pass streaming.
// Swapped QK^T (comb bf16 rides as MFMA C-init) -> raw exp2 -> PV via 16x16x16 MFMAs
// (A-fragment == QK^T C/D layout). Softmax denominator via ones-MFMA. PAIRED m-tiles:
// wave w processes (mt=w, mt=w+8) in ONE pass over the 22 K-tiles -- kf/v0/v1 LDS
// reads shared between the two Q-tiles and the two dependency chains interleave for
// 2x ILP. Tail tile (mt=w+16, w<6) single loop. All accumulators distinct named
// vars (rule #20 -- r9/r13/r19 spills all came from larger loop bodies/arrays).
__global__ __launch_bounds__(512, 6) void swin_attn(
        const bf16_t* __restrict__ qkv, const bf16_t* __restrict__ comb,
        bf16_t* __restrict__ attout) {
    __shared__ __align__(16) bf16_t Ksh[NPAD * 32];       // [n][d], swz ((n>>1)&3)<<3
    __shared__ __align__(16) bf16_t Vsh[32 * NPAD];       // [d][n], swz ((d>>1)&3)<<3
    const int t = threadIdx.x;
    const int bid = blockIdx.x;
    const int h = (bid & 127) >> 3;
    const int w = bid & 7;
    const int b = w + ((bid >> 7) << 3);                  // b = w + 8*j
    const int plane = h * 8 + w;
    const int wid = t >> 6, lane = t & 63;
    const int lm = lane & 15, g = lane >> 4;
    const int lkb = g << 3;
    const size_t rowbase = (size_t)b * SEQ;

    // stage K rows + V^T
    for (int base = 0; base < SEQ; base += 128) {
        int n = base + (t >> 2);
        int db = (t & 3) << 3;
        if (n < SEQ) {
            bf16x8 kv = *reinterpret_cast<const bf16x8*>(&qkv[(rowbase + n) * C3 + CH + h * HDIM + db]);
            *reinterpret_cast<bf16x8*>(&Ksh[(n * 32 + db) ^ (((n >> 1) & 3) << 3)]) = kv;
            bf16x8 vv = *reinterpret_cast<const bf16x8*>(&qkv[(rowbase + n) * C3 + 2 * CH + h * HDIM + db]);
#pragma unroll
            for (int e = 0; e < 8; ++e) {
                int d = db + e;
                Vsh[(d * NPAD + n) ^ (((d >> 1) & 3) << 3)] = vv[e];
            }
        }
    }
    if (t < 36) {
        int n = SEQ + (t >> 2), db = (t & 3) << 3;
        *reinterpret_cast<bf16x8*>(&Ksh[(n * 32 + db) ^ (((n >> 1) & 3) << 3)]) = bf8_zero();
    }
    for (int i = t; i < 32 * 9; i += 512) {
        int d = i / 9, n = SEQ + (i % 9);
        Vsh[(d * NPAD + n) ^ (((d >> 1) & 3) << 3)] = (bf16_t)0.f;
    }
    __syncthreads();

    const int kswz = ((lm >> 1) & 3) << 3;
    const int kbase = (lm * 32 + lkb) ^ kswz;       // K reads: base + nt*512 (imm offsets)
    // V bases: swizzle bits (elem 3,4) vs nt*16 stride collide only at elem bit 4
    // (nt parity) -> two precomputed XORed bases; (a+32u)^c == (a^c)+32u for c<=bit4.
    const int vb0e = (lm * NPAD + 4 * g) ^ kswz;
    const int vb0o = (lm * NPAD + 4 * g + 16) ^ kswz;
    const int vb1e = ((16 + lm) * NPAD + 4 * g) ^ kswz;
    const int vb1o = ((16 + lm) * NPAD + 4 * g + 16) ^ kswz;

    bf16x4 ones;
    ones[0] = (bf16_t)1.f; ones[1] = (bf16_t)1.f; ones[2] = (bf16_t)1.f; ones[3] = (bf16_t)1.f;

    // ---- paired tiles: mt_a = wid, mt_b = wid + 8 (both always < 22)
    {
        const int m0a = wid * 16, m0b = (wid + 8) * 16;
        bf16x8 qfa = *reinterpret_cast<const bf16x8*>(&qkv[(rowbase + m0a + lm) * C3 + h * HDIM + lkb]);
        bf16x8 qfb = *reinterpret_cast<const bf16x8*>(&qkv[(rowbase + m0b + lm) * C3 + h * HDIM + lkb]);

        f32x4 o0a = {0.f, 0.f, 0.f, 0.f}, o1a = {0.f, 0.f, 0.f, 0.f}, osa = {0.f, 0.f, 0.f, 0.f};
        f32x4 o0b = {0.f, 0.f, 0.f, 0.f}, o1b = {0.f, 0.f, 0.f, 0.f}, osb = {0.f, 0.f, 0.f, 0.f};
        const bf16x4* cpa = reinterpret_cast<const bf16x4*>(comb) + ((size_t)plane * NTILES + wid) * NTILES * 64;
        const bf16x4* cpb = reinterpret_cast<const bf16x4*>(comb) + ((size_t)plane * NTILES + wid + 8) * NTILES * 64;
#pragma unroll 2
        for (int nt = 0; nt < NTILES; ++nt) {
            bf16x4 cba = cpa[nt * 64 + lane];
            bf16x4 cbb = cpb[nt * 64 + lane];
            bf16x8 kf = *reinterpret_cast<const bf16x8*>(&Ksh[kbase + nt * 512]);
            f32x4 za, zb;
            za[0] = (float)cba[0]; za[1] = (float)cba[1]; za[2] = (float)cba[2]; za[3] = (float)cba[3];
            zb[0] = (float)cbb[0]; zb[1] = (float)cbb[1]; zb[2] = (float)cbb[2]; zb[3] = (float)cbb[3];
            f32x4 sa = mfma16(kf, qfa, za);
            f32x4 sb = mfma16(kf, qfb, zb);
            bf16x4 paa, pab;
#pragma unroll
            for (int r = 0; r < 4; ++r) {
                paa[r] = (bf16_t)__builtin_amdgcn_exp2f(sa[r]);
                pab[r] = (bf16_t)__builtin_amdgcn_exp2f(sb[r]);
            }
            const int off = (nt >> 1) * 32;
            bf16x4 v0 = *reinterpret_cast<const bf16x4*>(&Vsh[((nt & 1) ? vb0o : vb0e) + off]);
            bf16x4 v1 = *reinterpret_cast<const bf16x4*>(&Vsh[((nt & 1) ? vb1o : vb1e) + off]);
            o0a = mfma16k16(paa, v0, o0a);
            o0b = mfma16k16(pab, v0, o0b);
            o1a = mfma16k16(paa, v1, o1a);
            o1b = mfma16k16(pab, v1, o1b);
            osa = mfma16k16(paa, ones, osa);
            osb = mfma16k16(pab, ones, osb);
        }
#pragma unroll
        for (int r = 0; r < 4; ++r) {
            int gma = m0a + 4 * g + r;
            float iva = 1.f / osa[r];
            attout[(rowbase + gma) * CH + h * HDIM + lm]      = (bf16_t)(o0a[r] * iva);
            attout[(rowbase + gma) * CH + h * HDIM + 16 + lm] = (bf16_t)(o1a[r] * iva);
            int gmb = m0b + 4 * g + r;
            float ivb = 1.f / osb[r];
            attout[(rowbase + gmb) * CH + h * HDIM + lm]      = (bf16_t)(o0b[r] * ivb);
            attout[(rowbase + gmb) * CH + h * HDIM + 16 + lm] = (bf16_t)(o1b[r] * ivb);
        }
    }

    // ---- tail tile: mt = wid + 16 (only waves 0..5)
    if (wid < 6) {
        const int mt = wid + 16;
        const int m0 = mt * 16;
        // out-of-range q-rows read allocated pad rows; comb pad (-1e30) zeroes them
        bf16x8 qf = *reinterpret_cast<const bf16x8*>(&qkv[(rowbase + m0 + lm) * C3 + h * HDIM + lkb]);

        f32x4 o0 = {0.f, 0.f, 0.f, 0.f}, o1 = {0.f, 0.f, 0.f, 0.f};
        f32x4 osum = {0.f, 0.f, 0.f, 0.f};
        const bf16x4* cp = reinterpret_cast<const bf16x4*>(comb) + ((size_t)plane * NTILES + mt) * NTILES * 64;
#pragma unroll 2
        for (int nt = 0; nt < NTILES; ++nt) {
            bf16x4 cb = cp[nt * 64 + lane];
            bf16x8 kf = *reinterpret_cast<const bf16x8*>(&Ksh[kbase + nt * 512]);
            f32x4 z;
            z[0] = (float)cb[0]; z[1] = (float)cb[1]; z[2] = (float)cb[2]; z[3] = (float)cb[3];
            f32x4 s = mfma16(kf, qf, z);
            bf16x4 pa;
#pragma unroll
            for (int r = 0; r < 4; ++r)
                pa[r] = (bf16_t)__builtin_amdgcn_exp2f(s[r]);
            const int off = (nt >> 1) * 32;
            bf16x4 v0 = *reinterpret_cast<const bf16x4*>(&Vsh[((nt & 1) ? vb0o : vb0e) + off]);
            bf16x4 v1 = *reinterpret_cast<const bf16x4*>(&Vsh[((nt & 1) ? vb1o : vb1e) + off]);
            o0 = mfma16k16(pa, v0, o0);
            o1 = mfma16k16(pa, v1, o1);
            osum = mfma16k16(pa, ones, osum);
        }
#pragma unroll
        for (int r = 0; r < 4; ++r) {
            int gm = m0 + 4 * g + r;
            if (gm < SEQ) {
                float iv = 1.f / osum[r];
                attout[(rowbase + gm) * CH + h * HDIM + lm]      = (bf16_t)(o0[r] * iv);
                attout[(rowbase + gm) * CH + h * HDIM + 16 + lm] = (bf16_t)(o1[r] * iv);
            }
        }
    }
}

extern "C" void kernel_launch(void* const* d_in, const int* in_sizes, int n_in,
                              void* d_out, int out_size, void* d_ws, size_t ws_size,
                              hipStream_t stream) {
    const float* x          = (const float*)d_in[0];
    const float* mask       = (const float*)d_in[1];
    const float* w_qkv      = (const float*)d_in[2];
    const float* b_qkv      = (const float*)d_in[3];
    const float* w_proj     = (const float*)d_in[4];
    const float* b_proj     = (const float*)d_in[5];
    const float* bias_table = (const float*)d_in[6];
    const int*   rel_index  = (const int*)d_in[7];
    float* out = (float*)d_out;

    char* ws = (char*)d_ws;
    const size_t qkv_bytes = (size_t)MPAD * C3 * sizeof(bf16_t);   // 67,633,152
    const size_t xb_bytes  = (size_t)MPAD * CH * sizeof(bf16_t);   // 22,544,384
    const size_t bfq_bytes = (size_t)C3 * CH * sizeof(bf16_t);     //  1,572,864
    const size_t bfp_bytes = (size_t)CH * CH * sizeof(bf16_t);     //    524,288
    bf16_t* qkv    = (bf16_t*)ws;
    bf16_t* Xb     = (bf16_t*)(ws + qkv_bytes);           // reused as attout
    bf16_t* attout = Xb;
    bf16_t* Bfq    = (bf16_t*)(ws + qkv_bytes + xb_bytes);
    bf16_t* Bfp    = (bf16_t*)(ws + qkv_bytes + xb_bytes + bfq_bytes);
    bf16_t* comb   = (bf16_t*)(ws + qkv_bytes + xb_bytes + bfq_bytes + bfp_bytes);

    const int prep_grid = 5504 + 768 + 256 + NWIN * NTILES * 6;   // 6528 + 1056 = 7584
    hipLaunchKernelGGL(swin_prep, dim3(prep_grid), dim3(256), 0, stream,
                       x, w_qkv, w_proj, bias_table, rel_index, mask, Xb, Bfq, Bfp, comb);
    hipLaunchKernelGGL((swin_gemm<12, true>), dim3(MB_TILES * 12), dim3(256), 0, stream,
                       Xb, Bfq, b_qkv, (void*)qkv);
    hipLaunchKernelGGL(swin_attn, dim3(NUM_B * NH), dim3(512), 0, stream,
                       qkv, comb, attout);
    hipLaunchKernelGGL((swin_gemm<4, false>), dim3(MB_TILES * 4), dim3(256), 0, stream,
                       attout, Bfp, b_proj, (void*)out);
}

// Round 21
// 139.565 us; speedup vs baseline: 1.1957x; 1.0473x over previous
//
#include <hip/hip_runtime.h>

typedef __bf16 bf16_t;
typedef __bf16 bf16x4 __attribute__((ext_vector_type(4)));
typedef __bf16 bf16x8 __attribute__((ext_vector_type(8)));
typedef short  s16x4  __attribute__((ext_vector_type(4)));
typedef float  f32x4  __attribute__((ext_vector_type(4)));

#define NUM_B 64
#define SEQ   343
#define CH    512
#define NH    16
#define HDIM  32
#define NWIN  8
#define C3    1536
#define MTOT  (NUM_B * SEQ)      // 21952
#define MPAD  22016              // 172 * 128
#define NTILES 22
#define NPAD  352
#define NN    (SEQ * SEQ)
#define MB_TILES 172
#define QSCALE 0.17677669529663687f
#define LOG2E  1.4426950408889634f

__device__ __forceinline__ f32x4 mfma16(bf16x8 a, bf16x8 b, f32x4 c) {
    return __builtin_amdgcn_mfma_f32_16x16x32_bf16(a, b, c, 0, 0, 0);
}

// 16x16x16 bf16 MFMA: A-fragment = A[m=lane&15][k=4*(lane>>4)+e] -- matches the
// C/D layout of the swapped QK^T, so P^T needs NO data movement to become the
// PV A-operand.
__device__ __forceinline__ f32x4 mfma16k16(bf16x4 a, bf16x4 b, f32x4 c) {
    return __builtin_amdgcn_mfma_f32_16x16x16bf16_1k(
        __builtin_bit_cast(s16x4, a), __builtin_bit_cast(s16x4, b), c, 0, 0, 0);
}

__device__ __forceinline__ bf16x8 bf8_zero() {
    bf16x8 v;
#pragma unroll
    for (int i = 0; i < 8; ++i) v[i] = (bf16_t)0.f;
    return v;
}

__device__ __forceinline__ bf16x8 pack8(const float4& a, const float4& b) {
    bf16x8 v;
    v[0] = (bf16_t)a.x; v[1] = (bf16_t)a.y; v[2] = (bf16_t)a.z; v[3] = (bf16_t)a.w;
    v[4] = (bf16_t)b.x; v[5] = (bf16_t)b.y; v[6] = (bf16_t)b.z; v[7] = (bf16_t)b.w;
    return v;
}

__device__ __forceinline__ float f4get(const float4& v, int i) {
    return i == 0 ? v.x : i == 1 ? v.y : i == 2 ? v.z : v.w;
}

__device__ __forceinline__ void gload16(const void* g, void* l) {
    __builtin_amdgcn_global_load_lds(
        (const __attribute__((address_space(1))) void*)g,
        (__attribute__((address_space(3))) void*)l, 16, 0, 0);
}

// ---------------- comb block (LDS-free, gather-latency-bound) ----------------
// comb[plane=h*8+w][mt][nt][lane*4+r] = LOG2E * (bias + mask) at
// (gm = mt*16+(lane&15), gn = nt*16+4*(lane>>4)+r); pad -> -1e30.
// Runs INSIDE the qkv-GEMM launch: complementary bottleneck (no MFMA, pure
// gathers) fills the GEMM's idle issue slots; attn (next kernel) is the sync.
__device__ void comb_block(int cid, int t,
                           const float* __restrict__ bias_table,
                           const int* __restrict__ rel_index,
                           const float* __restrict__ mask,
                           bf16_t* __restrict__ comb) {
    const int ntq = cid % 6, mt = (cid / 6) % NTILES, w = cid / (6 * NTILES);
    const int nt = ntq * 4 + (t >> 6);
    if (nt >= NTILES) return;
    const int lane = t & 63;
    const int lm = lane & 15, g = lane >> 4;
    const int gm = mt * 16 + lm;
    const bool gmok = gm < SEQ;

    bool ok[4]; int idx[4]; float mv[4];
#pragma unroll
    for (int r = 0; r < 4; ++r) {
        int gn = nt * 16 + 4 * g + r;
        ok[r] = gmok && (gn < SEQ);
        int a = ok[r] ? gm * SEQ + gn : 0;
        idx[r] = rel_index[a];
        mv[r] = ok[r] ? mask[(size_t)w * NN + a] : 0.f;
    }
    const size_t outb = ((size_t)mt * NTILES + nt) * 64 + lane;   // bf16x4 units, within plane
    bf16x4* combv = reinterpret_cast<bf16x4*>(comb);
#pragma unroll
    for (int hq = 0; hq < 4; ++hq) {
        float4 b0 = *reinterpret_cast<const float4*>(&bias_table[idx[0] * NH + hq * 4]);
        float4 b1 = *reinterpret_cast<const float4*>(&bias_table[idx[1] * NH + hq * 4]);
        float4 b2 = *reinterpret_cast<const float4*>(&bias_table[idx[2] * NH + hq * 4]);
        float4 b3 = *reinterpret_cast<const float4*>(&bias_table[idx[3] * NH + hq * 4]);
#pragma unroll
        for (int hh = 0; hh < 4; ++hh) {
            int h = hq * 4 + hh;
            bf16x4 o;
            o[0] = ok[0] ? (bf16_t)((f4get(b0, hh) + mv[0]) * LOG2E) : (bf16_t)(-1e30f);
            o[1] = ok[1] ? (bf16_t)((f4get(b1, hh) + mv[1]) * LOG2E) : (bf16_t)(-1e30f);
            o[2] = ok[2] ? (bf16_t)((f4get(b2, hh) + mv[2]) * LOG2E) : (bf16_t)(-1e30f);
            o[3] = ok[3] ? (bf16_t)((f4get(b3, hh) + mv[3]) * LOG2E) : (bf16_t)(-1e30f);
            combv[(size_t)(h * 8 + w) * (NTILES * NTILES * 64) + outb] = o;
        }
    }
}

// ---------------- prep: X->bf16 (padded), W -> MFMA-fragment layout ----------
// Bfrag[n16][k32][lane][8] = W[k32*32 + (lane>>4)*8 + e][n16*16 + (lane&15)]:
// a wave's B-operand (16 cols x K=32) is ONE contiguous 1KB chunk -> B never
// touches LDS in the GEMM (L2-resident weights).
__global__ __launch_bounds__(256) void swin_prep(
        const float* __restrict__ X, const float* __restrict__ Wq,
        const float* __restrict__ Wp,
        bf16_t* __restrict__ Xb, bf16_t* __restrict__ Bfq, bf16_t* __restrict__ Bfp) {
    __shared__ __align__(16) float shbuf[32 * 33];
    const int bid = blockIdx.x, t = threadIdx.x;
    if (bid < 5504) {
        size_t e = ((size_t)bid * 256 + t) * 8;
        bf16x8 v;
        if (e < (size_t)MTOT * CH) {
            const float4* p = reinterpret_cast<const float4*>(&X[e]);
            v = pack8(p[0], p[1]);
        } else v = bf8_zero();
        *reinterpret_cast<bf16x8*>(&Xb[e]) = v;
        return;
    }
    float (*tile)[33] = reinterpret_cast<float(*)[33]>(shbuf);
    const float* src; bf16_t* dst; int srcN, k0, n0;
    if (bid < 6272) {
        int b2 = bid - 5504;               // Wq: 768 blocks (16 k-tiles x 48 n-tiles)
        k0 = (b2 % 16) * 32; n0 = (b2 / 16) * 32;
        src = Wq; dst = Bfq; srcN = C3;
    } else {
        int b2 = bid - 6272;               // Wp: 256 blocks
        k0 = (b2 % 16) * 32; n0 = (b2 / 16) * 32;
        src = Wp; dst = Bfp; srcN = CH;
    }
    int r = t >> 3, c4 = (t & 7) * 4;
    const float4 u = *reinterpret_cast<const float4*>(&src[(size_t)(k0 + r) * srcN + n0 + c4]);
    tile[r][c4 + 0] = u.x; tile[r][c4 + 1] = u.y; tile[r][c4 + 2] = u.z; tile[r][c4 + 3] = u.w;
    __syncthreads();
    // write fragment layout: t -> (sub n16-half, lane, elem-half)
    const int sub = t >> 7, lane2 = (t >> 1) & 63, half = t & 1;
    const int lm = lane2 & 15, g = lane2 >> 4;
    bf16x4 o;
#pragma unroll
    for (int e = 0; e < 4; ++e)
        o[e] = (bf16_t)tile[g * 8 + half * 4 + e][sub * 16 + lm];
    const size_t off = ((size_t)(((n0 >> 4) + sub) * 16 + (k0 >> 5)) * 64 + lane2) * 8 + half * 4;
    *reinterpret_cast<bf16x4*>(&dst[off]) = o;
}

// ---------------- pipelined bf16 GEMM: C = A[M][512] * W, B from L2 ----------------
// A: BK=32, 3-buffer LDS ring (24 KB), counted vmcnt, STAGE after barrier (race-free).
// B: MFMA-fragment loads straight from Bfrag (L2-resident), DEPTH-1 pipelined
// (bc <- bn; depth-2 regressed via VGPR/occupancy, r17). For QKV, the grid carries
// 1056 extra comb blocks interleaved every 3rd launch id (cheap gather blocks fill
// the barrier-paced GEMM's issue slack; attn kernel boundary is the comb sync).
template <int NB, bool QKV>
__global__ __launch_bounds__(256) void swin_gemm(
        const bf16_t* __restrict__ A, const bf16_t* __restrict__ Bf,
        const float* __restrict__ bias, void* __restrict__ outv,
        const float* __restrict__ bias_table, const int* __restrict__ rel_index,
        const float* __restrict__ mask, bf16_t* __restrict__ comb) {
    __shared__ __align__(16) bf16_t shraw[17408];         // 34816 B: ring 24576 | epilogue
    int bid;
    if constexpr (QKV) {
        const int rb2 = blockIdx.x;                       // grid = 3096 + 24 = 3120
        if (rb2 >= 3096) { comb_block(1032 + (rb2 - 3096), threadIdx.x, bias_table, rel_index, mask, comb); return; }
        if (rb2 % 3 == 2) { comb_block(rb2 / 3, threadIdx.x, bias_table, rel_index, mask, comb); return; }
        bid = (rb2 / 3) * 2 + (rb2 % 3);                  // gemm ordinal in [0, 2064)
    } else {
        bid = blockIdx.x;
    }
    const int nwg8 = MB_TILES * NB / 8;
    bid = (bid & 7) * nwg8 + (bid >> 3);                  // XCD-chunked swizzle
    const int nb = bid % NB, mb = bid / NB;
    const int m0 = mb * 128, n0 = nb * 128;
    const int t = threadIdx.x, wid = t >> 6, lane = t & 63;
    const int wr = wid >> 1, wc = wid & 1;
    const int lm = lane & 15, g = lane >> 4;
    const int swr = ((lane >> 2) ^ (lane >> 4)) & 3;
    const bf16_t* gA = &A[(size_t)(m0 + wid * 32 + (lane >> 2)) * CH + (((lane & 3) ^ swr) << 3)];
    const int soff = ((g ^ ((lm ^ (lm >> 2)) & 3)) << 3);
    // B fragment base: n16 tiles (n0>>4)+wc*4+j, k32 tile = kt; 8192 elems per n16
    const bf16_t* gBf = &Bf[((size_t)((n0 >> 4) + wc * 4) * 16) * 512 + lane * 8];

    f32x4 acc[4][4];
#pragma unroll
    for (int i = 0; i < 4; ++i)
#pragma unroll
        for (int j = 0; j < 4; ++j) {
            acc[i][j][0] = 0.f; acc[i][j][1] = 0.f; acc[i][j][2] = 0.f; acc[i][j][3] = 0.f;
        }

#define STAGE(tile, buf)                                                          \
    do {                                                                          \
        const int _k0 = (tile) * 32;                                              \
        gload16(gA + _k0,           &shraw[(buf) * 4096 + (wid * 32 + 0) * 32]);  \
        gload16(gA + _k0 + 16 * CH, &shraw[(buf) * 4096 + (wid * 32 + 16) * 32]); \
    } while (0)

    STAGE(0, 0);
    STAGE(1, 1);
    bf16x8 bc[4], bn[4];
#pragma unroll
    for (int j = 0; j < 4; ++j)
        bc[j] = *reinterpret_cast<const bf16x8*>(gBf + (size_t)j * 8192);

#pragma unroll
    for (int kt = 0; kt < 16; ++kt) {
        // outstanding at most: A-stage(kt+1) [2] + b(kt) [4] -> stage(kt) is older, done
        if (kt <= 14) asm volatile("s_waitcnt vmcnt(6)" ::: "memory");
        else          asm volatile("s_waitcnt vmcnt(4)" ::: "memory");
        __builtin_amdgcn_s_barrier();
        __builtin_amdgcn_sched_barrier(0);
        if (kt <= 13) STAGE(kt + 2, (kt + 2) % 3);        // after barrier: 3-ring safe
        if (kt <= 14) {
#pragma unroll
            for (int j = 0; j < 4; ++j)
                bn[j] = *reinterpret_cast<const bf16x8*>(gBf + (size_t)j * 8192 + (kt + 1) * 512);
        }
        const int buf = kt % 3;
        bf16x8 a[4];
#pragma unroll
        for (int i = 0; i < 4; ++i)
            a[i] = *reinterpret_cast<const bf16x8*>(&shraw[buf * 4096 + (wr * 64 + i * 16 + lm) * 32 + soff]);
        __builtin_amdgcn_s_setprio(1);
#pragma unroll
        for (int i = 0; i < 4; ++i)
#pragma unroll
            for (int j = 0; j < 4; ++j)
                acc[i][j] = mfma16(a[i], bc[j], acc[i][j]);
        __builtin_amdgcn_s_setprio(0);
        if (kt <= 14) {
#pragma unroll
            for (int j = 0; j < 4; ++j) bc[j] = bn[j];
        }
    }
#undef STAGE
    __syncthreads();   // full drain once before LDS reuse in epilogue

    // epilogue: LDS transpose -> coalesced stores
    const int rb = (lane >> 4) << 2;
    if (QKV) {
        bf16_t* Cs = &shraw[0];                           // [128][136] bf16 = 34816 B
#pragma unroll
        for (int j = 0; j < 4; ++j) {
            int col = wc * 64 + j * 16 + lm;
            float bv = bias[n0 + col];
            float sc = (n0 + col < CH) ? (QSCALE * LOG2E) : 1.0f;   // Q pre-scale incl. log2e
#pragma unroll
            for (int i = 0; i < 4; ++i)
#pragma unroll
                for (int r = 0; r < 4; ++r)
                    Cs[(wr * 64 + i * 16 + rb + r) * 136 + col] = (bf16_t)((acc[i][j][r] + bv) * sc);
        }
        __syncthreads();
        bf16_t* outp = (bf16_t*)outv;
#pragma unroll
        for (int it = 0; it < 8; ++it) {
            int row = (t >> 4) + it * 16;
            int c8 = (t & 15) * 8;
            bf16x8 v = *reinterpret_cast<const bf16x8*>(&Cs[row * 136 + c8]);
            int grow = m0 + row;
            if (grow < MTOT)
                *reinterpret_cast<bf16x8*>(&outp[(size_t)grow * (NB * 128) + n0 + c8]) = v;
        }
    } else {
        // fp32 transpose in two 64-row halves (32 KB each, fits 34816 B)
        float* fCs = reinterpret_cast<float*>(&shraw[0]);     // [64][128] fp32
        float* outp = (float*)outv;
#pragma unroll
        for (int half = 0; half < 2; ++half) {
            __syncthreads();
            if (wr == half) {
#pragma unroll
                for (int j = 0; j < 4; ++j) {
                    int col = wc * 64 + j * 16 + lm;
                    float bv = bias[n0 + col];
#pragma unroll
                    for (int i = 0; i < 4; ++i)
#pragma unroll
                        for (int r = 0; r < 4; ++r)
                            fCs[(i * 16 + rb + r) * 128 + col] = acc[i][j][r] + bv;
                }
            }
            __syncthreads();
#pragma unroll
            for (int it = 0; it < 8; ++it) {
                int row = (t >> 5) + it * 8;              // 0..63
                int c4 = (t & 31) * 4;
                float4 v = *reinterpret_cast<const float4*>(&fCs[row * 128 + c4]);
                int grow = m0 + half * 64 + row;
                if (grow < MTOT)
                    *reinterpret_cast<float4*>(&outp[(size_t)grow * (NB * 128) + n0 + c4]) = v;
            }
        }
    }
}

// ---------------- attention: one block (8 waves) per (b,h); single-pass streaming.
// Swapped QK^T (comb bf16 rides as MFMA C-init) -> raw exp2 -> PV via 16x16x16 MFMAs
// (A-fragment == QK^T C/D layout). Softmax denominator via ones-MFMA. PAIRED m-tiles:
// wave w processes (mt=w, mt=w+8) in ONE pass over the 22 K-tiles -- kf/v0/v1 LDS
// reads shared between the two Q-tiles and the two dependency chains interleave for
// 2x ILP. Tail tile (mt=w+16, w<6) single loop. All accumulators distinct named
// vars (rule #20 -- r9/r13/r19 spills all came from larger loop bodies/arrays).
__global__ __launch_bounds__(512, 6) void swin_attn(
        const bf16_t* __restrict__ qkv, const bf16_t* __restrict__ comb,
        bf16_t* __restrict__ attout) {
    __shared__ __align__(16) bf16_t Ksh[NPAD * 32];       // [n][d], swz ((n>>1)&3)<<3
    __shared__ __align__(16) bf16_t Vsh[32 * NPAD];       // [d][n], swz ((d>>1)&3)<<3
    const int t = threadIdx.x;
    const int bid = blockIdx.x;
    const int h = (bid & 127) >> 3;
    const int w = bid & 7;
    const int b = w + ((bid >> 7) << 3);                  // b = w + 8*j
    const int plane = h * 8 + w;
    const int wid = t >> 6, lane = t & 63;
    const int lm = lane & 15, g = lane >> 4;
    const int lkb = g << 3;
    const size_t rowbase = (size_t)b * SEQ;

    // stage K rows + V^T
    for (int base = 0; base < SEQ; base += 128) {
        int n = base + (t >> 2);
        int db = (t & 3) << 3;
        if (n < SEQ) {
            bf16x8 kv = *reinterpret_cast<const bf16x8*>(&qkv[(rowbase + n) * C3 + CH + h * HDIM + db]);
            *reinterpret_cast<bf16x8*>(&Ksh[(n * 32 + db) ^ (((n >> 1) & 3) << 3)]) = kv;
            bf16x8 vv = *reinterpret_cast<const bf16x8*>(&qkv[(rowbase + n) * C3 + 2 * CH + h * HDIM + db]);
#pragma unroll
            for (int e = 0; e < 8; ++e) {
                int d = db + e;
                Vsh[(d * NPAD + n) ^ (((d >> 1) & 3) << 3)] = vv[e];
            }
        }
    }
    if (t < 36) {
        int n = SEQ + (t >> 2), db = (t & 3) << 3;
        *reinterpret_cast<bf16x8*>(&Ksh[(n * 32 + db) ^ (((n >> 1) & 3) << 3)]) = bf8_zero();
    }
    for (int i = t; i < 32 * 9; i += 512) {
        int d = i / 9, n = SEQ + (i % 9);
        Vsh[(d * NPAD + n) ^ (((d >> 1) & 3) << 3)] = (bf16_t)0.f;
    }
    __syncthreads();

    const int kswz = ((lm >> 1) & 3) << 3;
    const int kbase = (lm * 32 + lkb) ^ kswz;       // K reads: base + nt*512 (imm offsets)
    // V bases: swizzle bits (elem 3,4) vs nt*16 stride collide only at elem bit 4
    // (nt parity) -> two precomputed XORed bases; (a+32u)^c == (a^c)+32u for c<=bit4.
    const int vb0e = (lm * NPAD + 4 * g) ^ kswz;
    const int vb0o = (lm * NPAD + 4 * g + 16) ^ kswz;
    const int vb1e = ((16 + lm) * NPAD + 4 * g) ^ kswz;
    const int vb1o = ((16 + lm) * NPAD + 4 * g + 16) ^ kswz;

    bf16x4 ones;
    ones[0] = (bf16_t)1.f; ones[1] = (bf16_t)1.f; ones[2] = (bf16_t)1.f; ones[3] = (bf16_t)1.f;

    // ---- paired tiles: mt_a = wid, mt_b = wid + 8 (both always < 22)
    {
        const int m0a = wid * 16, m0b = (wid + 8) * 16;
        bf16x8 qfa = *reinterpret_cast<const bf16x8*>(&qkv[(rowbase + m0a + lm) * C3 + h * HDIM + lkb]);
        bf16x8 qfb = *reinterpret_cast<const bf16x8*>(&qkv[(rowbase + m0b + lm) * C3 + h * HDIM + lkb]);

        f32x4 o0a = {0.f, 0.f, 0.f, 0.f}, o1a = {0.f, 0.f, 0.f, 0.f}, osa = {0.f, 0.f, 0.f, 0.f};
        f32x4 o0b = {0.f, 0.f, 0.f, 0.f}, o1b = {0.f, 0.f, 0.f, 0.f}, osb = {0.f, 0.f, 0.f, 0.f};
        const bf16x4* cpa = reinterpret_cast<const bf16x4*>(comb) + ((size_t)plane * NTILES + wid) * NTILES * 64;
        const bf16x4* cpb = reinterpret_cast<const bf16x4*>(comb) + ((size_t)plane * NTILES + wid + 8) * NTILES * 64;
#pragma unroll 2
        for (int nt = 0; nt < NTILES; ++nt) {
            bf16x4 cba = cpa[nt * 64 + lane];
            bf16x4 cbb = cpb[nt * 64 + lane];
            bf16x8 kf = *reinterpret_cast<const bf16x8*>(&Ksh[kbase + nt * 512]);
            f32x4 za, zb;
            za[0] = (float)cba[0]; za[1] = (float)cba[1]; za[2] = (float)cba[2]; za[3] = (float)cba[3];
            zb[0] = (float)cbb[0]; zb[1] = (float)cbb[1]; zb[2] = (float)cbb[2]; zb[3] = (float)cbb[3];
            f32x4 sa = mfma16(kf, qfa, za);
            f32x4 sb = mfma16(kf, qfb, zb);
            bf16x4 paa, pab;
#pragma unroll
            for (int r = 0; r < 4; ++r) {
                paa[r] = (bf16_t)__builtin_amdgcn_exp2f(sa[r]);
                pab[r] = (bf16_t)__builtin_amdgcn_exp2f(sb[r]);
            }
            const int off = (nt >> 1) * 32;
            bf16x4 v0 = *reinterpret_cast<const bf16x4*>(&Vsh[((nt & 1) ? vb0o : vb0e) + off]);
            bf16x4 v1 = *reinterpret_cast<const bf16x4*>(&Vsh[((nt & 1) ? vb1o : vb1e) + off]);
            o0a = mfma16k16(paa, v0, o0a);
            o0b = mfma16k16(pab, v0, o0b);
            o1a = mfma16k16(paa, v1, o1a);
            o1b = mfma16k16(pab, v1, o1b);
            osa = mfma16k16(paa, ones, osa);
            osb = mfma16k16(pab, ones, osb);
        }
#pragma unroll
        for (int r = 0; r < 4; ++r) {
            int gma = m0a + 4 * g + r;
            float iva = 1.f / osa[r];
            attout[(rowbase + gma) * CH + h * HDIM + lm]      = (bf16_t)(o0a[r] * iva);
            attout[(rowbase + gma) * CH + h * HDIM + 16 + lm] = (bf16_t)(o1a[r] * iva);
            int gmb = m0b + 4 * g + r;
            float ivb = 1.f / osb[r];
            attout[(rowbase + gmb) * CH + h * HDIM + lm]      = (bf16_t)(o0b[r] * ivb);
            attout[(rowbase + gmb) * CH + h * HDIM + 16 + lm] = (bf16_t)(o1b[r] * ivb);
        }
    }

    // ---- tail tile: mt = wid + 16 (only waves 0..5)
    if (wid < 6) {
        const int mt = wid + 16;
        const int m0 = mt * 16;
        // out-of-range q-rows read allocated pad rows; comb pad (-1e30) zeroes them
        bf16x8 qf = *reinterpret_cast<const bf16x8*>(&qkv[(rowbase + m0 + lm) * C3 + h * HDIM + lkb]);

        f32x4 o0 = {0.f, 0.f, 0.f, 0.f}, o1 = {0.f, 0.f, 0.f, 0.f};
        f32x4 osum = {0.f, 0.f, 0.f, 0.f};
        const bf16x4* cp = reinterpret_cast<const bf16x4*>(comb) + ((size_t)plane * NTILES + mt) * NTILES * 64;
#pragma unroll 2
        for (int nt = 0; nt < NTILES; ++nt) {
            bf16x4 cb = cp[nt * 64 + lane];
            bf16x8 kf = *reinterpret_cast<const bf16x8*>(&Ksh[kbase + nt * 512]);
            f32x4 z;
            z[0] = (float)cb[0]; z[1] = (float)cb[1]; z[2] = (float)cb[2]; z[3] = (float)cb[3];
            f32x4 s = mfma16(kf, qf, z);
            bf16x4 pa;
#pragma unroll
            for (int r = 0; r < 4; ++r)
                pa[r] = (bf16_t)__builtin_amdgcn_exp2f(s[r]);
            const int off = (nt >> 1) * 32;
            bf16x4 v0 = *reinterpret_cast<const bf16x4*>(&Vsh[((nt & 1) ? vb0o : vb0e) + off]);
            bf16x4 v1 = *reinterpret_cast<const bf16x4*>(&Vsh[((nt & 1) ? vb1o : vb1e) + off]);
            o0 = mfma16k16(pa, v0, o0);
            o1 = mfma16k16(pa, v1, o1);
            osum = mfma16k16(pa, ones, osum);
        }
#pragma unroll
        for (int r = 0; r < 4; ++r) {
            int gm = m0 + 4 * g + r;
            if (gm < SEQ) {
                float iv = 1.f / osum[r];
                attout[(rowbase + gm) * CH + h * HDIM + lm]      = (bf16_t)(o0[r] * iv);
                attout[(rowbase + gm) * CH + h * HDIM + 16 + lm] = (bf16_t)(o1[r] * iv);
            }
        }
    }
}

extern "C" void kernel_launch(void* const* d_in, const int* in_sizes, int n_in,
                              void* d_out, int out_size, void* d_ws, size_t ws_size,
                              hipStream_t stream) {
    const float* x          = (const float*)d_in[0];
    const float* mask       = (const float*)d_in[1];
    const float* w_qkv      = (const float*)d_in[2];
    const float* b_qkv      = (const float*)d_in[3];
    const float* w_proj     = (const float*)d_in[4];
    const float* b_proj     = (const float*)d_in[5];
    const float* bias_table = (const float*)d_in[6];
    const int*   rel_index  = (const int*)d_in[7];
    float* out = (float*)d_out;

    char* ws = (char*)d_ws;
    const size_t qkv_bytes = (size_t)MPAD * C3 * sizeof(bf16_t);   // 67,633,152
    const size_t xb_bytes  = (size_t)MPAD * CH * sizeof(bf16_t);   // 22,544,384
    const size_t bfq_bytes = (size_t)C3 * CH * sizeof(bf16_t);     //  1,572,864
    const size_t bfp_bytes = (size_t)CH * CH * sizeof(bf16_t);     //    524,288
    bf16_t* qkv    = (bf16_t*)ws;
    bf16_t* Xb     = (bf16_t*)(ws + qkv_bytes);           // reused as attout
    bf16_t* attout = Xb;
    bf16_t* Bfq    = (bf16_t*)(ws + qkv_bytes + xb_bytes);
    bf16_t* Bfp    = (bf16_t*)(ws + qkv_bytes + xb_bytes + bfq_bytes);
    bf16_t* comb   = (bf16_t*)(ws + qkv_bytes + xb_bytes + bfq_bytes + bfp_bytes);

    // prep: X convert (5504) + W transposes (1024) = 6528 blocks; comb moved into qkv GEMM
    hipLaunchKernelGGL(swin_prep, dim3(6528), dim3(256), 0, stream,
                       x, w_qkv, w_proj, Xb, Bfq, Bfp);
    // qkv GEMM grid: 2064 gemm blocks + 1056 comb blocks interleaved (3096 + 24 tail)
    hipLaunchKernelGGL((swin_gemm<12, true>), dim3(3120), dim3(256), 0, stream,
                       Xb, Bfq, b_qkv, (void*)qkv, bias_table, rel_index, mask, comb);
    hipLaunchKernelGGL(swin_attn, dim3(NUM_B * NH), dim3(512), 0, stream,
                       qkv, comb, attout);
    hipLaunchKernelGGL((swin_gemm<4, false>), dim3(MB_TILES * 4), dim3(256), 0, stream,
                       attout, Bfp, b_proj, (void*)out, nullptr, nullptr, nullptr, nullptr);
}